// Round 1
// baseline (3077.058 us; speedup 1.0000x reference)
//
#include <hip/hip_runtime.h>

#define NN 50000
#define EE 800000
#define HD 256

// ---------------- GEMM: C[M,Ncol] = act(A[M,K] @ B[K,Ncol] + bias) ----------------
// ACT: 0=none, 1=leaky_relu(0.01), 2=relu
template<int BM, int BN, int BK, int TM, int TN, int ACT>
__global__ __launch_bounds__(256) void gemm_f32(
    const float* __restrict__ A, int lda,
    const float* __restrict__ B, int ldb,
    const float* __restrict__ bias,
    float* __restrict__ C, int ldc, int coff,
    int M, int Ncol, int K)
{
    constexpr int TX = BN / TN;
    constexpr int TY = BM / TM;
    static_assert(TX * TY == 256, "thread grid must be 256");
    __shared__ float As[BK][BM + 4];
    __shared__ float Bs[BK][BN + 4];

    const int tid = threadIdx.x;
    const int tx = tid % TX, ty = tid / TX;
    const int brow = blockIdx.y * BM;
    const int bcol = blockIdx.x * BN;

    float acc[TM][TN];
#pragma unroll
    for (int i = 0; i < TM; i++)
#pragma unroll
        for (int j = 0; j < TN; j++) acc[i][j] = 0.f;

    for (int k0 = 0; k0 < K; k0 += BK) {
        // stage A tile (BM x BK) -> As[k][m]
#pragma unroll
        for (int idx = tid; idx < BM * BK; idx += 256) {
            int m = idx / BK, k = idx % BK;
            int gr = brow + m, gk = k0 + k;
            As[k][m] = (gr < M && gk < K) ? A[(size_t)gr * lda + gk] : 0.f;
        }
        // stage B tile (BK x BN) -> Bs[k][n]
#pragma unroll
        for (int idx = tid; idx < BK * BN; idx += 256) {
            int k = idx / BN, n = idx % BN;
            int gk = k0 + k, gc = bcol + n;
            Bs[k][n] = (gk < K && gc < Ncol) ? B[(size_t)gk * ldb + gc] : 0.f;
        }
        __syncthreads();
#pragma unroll
        for (int k = 0; k < BK; k++) {
            float a[TM], b[TN];
#pragma unroll
            for (int i = 0; i < TM; i++) a[i] = As[k][ty * TM + i];
#pragma unroll
            for (int j = 0; j < TN; j++) b[j] = Bs[k][tx * TN + j];
#pragma unroll
            for (int i = 0; i < TM; i++)
#pragma unroll
                for (int j = 0; j < TN; j++) acc[i][j] = fmaf(a[i], b[j], acc[i][j]);
        }
        __syncthreads();
    }

#pragma unroll
    for (int i = 0; i < TM; i++) {
        int gr = brow + ty * TM + i;
        if (gr >= M) continue;
#pragma unroll
        for (int j = 0; j < TN; j++) {
            int gc = bcol + tx * TN + j;
            if (gc >= Ncol) continue;
            float v = acc[i][j] + bias[gc];
            if (ACT == 1) v = v > 0.f ? v : 0.01f * v;
            else if (ACT == 2) v = fmaxf(v, 0.f);
            C[(size_t)gr * ldc + coff + gc] = v;
        }
    }
}

// ---------------- edge counting + inverse ----------------
__global__ void count_edges(const int* __restrict__ ei, const int* __restrict__ et,
                            float* __restrict__ cnt)
{
    int e = blockIdx.x * blockDim.x + threadIdx.x;
    if (e < EE) {
        int dst = ei[EE + e];
        int r = et[e];
        atomicAdd(&cnt[(size_t)r * NN + dst], 1.0f);
    }
}

__global__ void inv_cnt_kernel(float* __restrict__ cnt)
{
    int i = blockIdx.x * blockDim.x + threadIdx.x;
    if (i < 2 * NN) cnt[i] = 1.0f / fmaxf(cnt[i], 1.0f);
}

// ---------------- scatter: out[dst,:] += h_rel[et,src,:] * inv[et,dst] ----------------
// one wave per edge, 4 edges per 256-thread block
__global__ __launch_bounds__(256) void scatter_mean(
    const float* __restrict__ hrel,   // [2, N, HD]
    const int* __restrict__ ei,       // [2, E]
    const int* __restrict__ et,       // [E]
    const float* __restrict__ inv,    // [2, N]
    float* __restrict__ out)          // [N, HD], pre-initialized with h_root
{
    int e = blockIdx.x * 4 + (threadIdx.x >> 6);
    if (e >= EE) return;
    int lane = threadIdx.x & 63;
    int src = ei[e];
    int dst = ei[EE + e];
    int r = et[e];
    float s = inv[(size_t)r * NN + dst];
    const float* row = hrel + ((size_t)r * NN + src) * HD;
    float* orow = out + (size_t)dst * HD;
#pragma unroll
    for (int j = 0; j < 4; j++) {
        int h = j * 64 + lane;
        atomicAdd(&orow[h], row[h] * s);
    }
}

// ---------------- output head: out[n,c] = x[n,:] @ w_out[:,c] + b_out[c] ----------------
__global__ __launch_bounds__(256) void out_proj(
    const float* __restrict__ x, const float* __restrict__ w,
    const float* __restrict__ b, float* __restrict__ out)
{
    int n = blockIdx.x * 4 + (threadIdx.x >> 6);
    if (n >= NN) return;
    int lane = threadIdx.x & 63;
    const float4* xr4 = (const float4*)(x + (size_t)n * HD);
    float4 v = xr4[lane];
    int k = lane * 4;
    float a0 = v.x * w[(k + 0) * 2 + 0] + v.y * w[(k + 1) * 2 + 0]
             + v.z * w[(k + 2) * 2 + 0] + v.w * w[(k + 3) * 2 + 0];
    float a1 = v.x * w[(k + 0) * 2 + 1] + v.y * w[(k + 1) * 2 + 1]
             + v.z * w[(k + 2) * 2 + 1] + v.w * w[(k + 3) * 2 + 1];
#pragma unroll
    for (int off = 32; off > 0; off >>= 1) {
        a0 += __shfl_down(a0, off);
        a1 += __shfl_down(a1, off);
    }
    if (lane == 0) {
        out[(size_t)n * 2 + 0] = a0 + b[0];
        out[(size_t)n * 2 + 1] = a1 + b[1];
    }
}

extern "C" void kernel_launch(void* const* d_in, const int* in_sizes, int n_in,
                              void* d_out, int out_size, void* d_ws, size_t ws_size,
                              hipStream_t stream)
{
    const float* des   = (const float*)d_in[0];
    const float* tweet = (const float*)d_in[1];
    const float* nump  = (const float*)d_in[2];
    const float* catp  = (const float*)d_in[3];
    const int*   ei    = (const int*)d_in[4];
    const int*   et    = (const int*)d_in[5];
    const float* w_des = (const float*)d_in[6],  *b_des = (const float*)d_in[7];
    const float* w_tw  = (const float*)d_in[8],  *b_tw  = (const float*)d_in[9];
    const float* w_num = (const float*)d_in[10], *b_num = (const float*)d_in[11];
    const float* w_cat = (const float*)d_in[12], *b_cat = (const float*)d_in[13];
    const float* w_in  = (const float*)d_in[14], *b_in  = (const float*)d_in[15];
    const float* weight1 = (const float*)d_in[16], *root1 = (const float*)d_in[17], *bias1 = (const float*)d_in[18];
    const float* weight2 = (const float*)d_in[19], *root2 = (const float*)d_in[20], *bias2 = (const float*)d_in[21];
    const float* w_out = (const float*)d_in[22], *b_out = (const float*)d_in[23];
    float* outp = (float*)d_out;

    // workspace carve-up (floats): x[N*HD], y[N*HD], hrel[2*N*HD], cnt[2*N]
    float* x    = (float*)d_ws;
    float* y    = x + (size_t)NN * HD;
    float* hrel = y + (size_t)NN * HD;
    float* cnt  = hrel + (size_t)2 * NN * HD;

    // edge counts -> inverse (shared across both layers)
    hipMemsetAsync(cnt, 0, (size_t)2 * NN * sizeof(float), stream);
    count_edges<<<(EE + 255) / 256, 256, 0, stream>>>(ei, et, cnt);
    inv_cnt_kernel<<<(2 * NN + 255) / 256, 256, 0, stream>>>(cnt);

    // ---- feature projections into columns of x (leaky relu) ----
    dim3 g64(1, (NN + 63) / 64);
    gemm_f32<64, 64, 16, 4, 4, 1><<<g64, 256, 0, stream>>>(des,   768, w_des, 64, b_des, x, HD, 0,   NN, 64, 768);
    gemm_f32<64, 64, 16, 4, 4, 1><<<g64, 256, 0, stream>>>(tweet, 768, w_tw,  64, b_tw,  x, HD, 64,  NN, 64, 768);
    gemm_f32<64, 64, 16, 4, 4, 1><<<g64, 256, 0, stream>>>(nump,  5,   w_num, 64, b_num, x, HD, 128, NN, 64, 5);
    gemm_f32<64, 64, 16, 4, 4, 1><<<g64, 256, 0, stream>>>(catp,  3,   w_cat, 64, b_cat, x, HD, 192, NN, 64, 3);

    // ---- x = lrelu(x @ w_in + b_in) -> y ----
    dim3 gbig(HD / 64, (NN + 127) / 128);
    gemm_f32<128, 64, 16, 8, 4, 1><<<gbig, 256, 0, stream>>>(x, HD, w_in, HD, b_in, y, HD, 0, NN, HD, HD);

    // ---- RGCN layer 1: read y, hrel = relu(y@W_r + b1), x = relu(y@root1 + b1) ----
    gemm_f32<128, 64, 16, 8, 4, 2><<<gbig, 256, 0, stream>>>(y, HD, weight1,            HD, bias1, hrel,                    HD, 0, NN, HD, HD);
    gemm_f32<128, 64, 16, 8, 4, 2><<<gbig, 256, 0, stream>>>(y, HD, weight1 + HD * HD,  HD, bias1, hrel + (size_t)NN * HD,  HD, 0, NN, HD, HD);
    gemm_f32<128, 64, 16, 8, 4, 2><<<gbig, 256, 0, stream>>>(y, HD, root1,              HD, bias1, x,                       HD, 0, NN, HD, HD);
    scatter_mean<<<(EE + 3) / 4, 256, 0, stream>>>(hrel, ei, et, cnt, x);

    // ---- RGCN layer 2: read x, hrel = relu(x@W_r + b2), y = relu(x@root2 + b2) ----
    gemm_f32<128, 64, 16, 8, 4, 2><<<gbig, 256, 0, stream>>>(x, HD, weight2,            HD, bias2, hrel,                    HD, 0, NN, HD, HD);
    gemm_f32<128, 64, 16, 8, 4, 2><<<gbig, 256, 0, stream>>>(x, HD, weight2 + HD * HD,  HD, bias2, hrel + (size_t)NN * HD,  HD, 0, NN, HD, HD);
    gemm_f32<128, 64, 16, 8, 4, 2><<<gbig, 256, 0, stream>>>(x, HD, root2,              HD, bias2, y,                       HD, 0, NN, HD, HD);
    scatter_mean<<<(EE + 3) / 4, 256, 0, stream>>>(hrel, ei, et, cnt, y);

    // ---- logits ----
    out_proj<<<(NN + 3) / 4, 256, 0, stream>>>(y, w_out, b_out, outp);
}

// Round 2
// 2329.672 us; speedup vs baseline: 1.3208x; 1.3208x over previous
//
#include <hip/hip_runtime.h>

#define NN 50000
#define EE 800000
#define HD 256
#define NSEG (2 * NN)

// ---------------- GEMM: C[M,Ncol] = act(A[M,K] @ B[K,Ncol] + bias) ----------------
// ACT: 0=none, 1=leaky_relu(0.01), 2=relu
template<int BM, int BN, int BK, int TM, int TN, int ACT>
__global__ __launch_bounds__(256) void gemm_f32(
    const float* __restrict__ A, int lda,
    const float* __restrict__ B, int ldb,
    const float* __restrict__ bias,
    float* __restrict__ C, int ldc, int coff,
    int M, int Ncol, int K)
{
    constexpr int TX = BN / TN;
    constexpr int TY = BM / TM;
    static_assert(TX * TY == 256, "thread grid must be 256");
    __shared__ float As[BK][BM + 4];
    __shared__ float Bs[BK][BN + 4];

    const int tid = threadIdx.x;
    const int tx = tid % TX, ty = tid / TX;
    const int brow = blockIdx.y * BM;
    const int bcol = blockIdx.x * BN;

    float acc[TM][TN];
#pragma unroll
    for (int i = 0; i < TM; i++)
#pragma unroll
        for (int j = 0; j < TN; j++) acc[i][j] = 0.f;

    for (int k0 = 0; k0 < K; k0 += BK) {
#pragma unroll
        for (int idx = tid; idx < BM * BK; idx += 256) {
            int m = idx / BK, k = idx % BK;
            int gr = brow + m, gk = k0 + k;
            As[k][m] = (gr < M && gk < K) ? A[(size_t)gr * lda + gk] : 0.f;
        }
#pragma unroll
        for (int idx = tid; idx < BK * BN; idx += 256) {
            int k = idx / BN, n = idx % BN;
            int gk = k0 + k, gc = bcol + n;
            Bs[k][n] = (gk < K && gc < Ncol) ? B[(size_t)gk * ldb + gc] : 0.f;
        }
        __syncthreads();
#pragma unroll
        for (int k = 0; k < BK; k++) {
            float a[TM], b[TN];
#pragma unroll
            for (int i = 0; i < TM; i++) a[i] = As[k][ty * TM + i];
#pragma unroll
            for (int j = 0; j < TN; j++) b[j] = Bs[k][tx * TN + j];
#pragma unroll
            for (int i = 0; i < TM; i++)
#pragma unroll
                for (int j = 0; j < TN; j++) acc[i][j] = fmaf(a[i], b[j], acc[i][j]);
        }
        __syncthreads();
    }

#pragma unroll
    for (int i = 0; i < TM; i++) {
        int gr = brow + ty * TM + i;
        if (gr >= M) continue;
#pragma unroll
        for (int j = 0; j < TN; j++) {
            int gc = bcol + tx * TN + j;
            if (gc >= Ncol) continue;
            float v = acc[i][j] + bias[gc];
            if (ACT == 1) v = v > 0.f ? v : 0.01f * v;
            else if (ACT == 2) v = fmaxf(v, 0.f);
            C[(size_t)gr * ldc + coff + gc] = v;
        }
    }
}

// ---------------- CSR build: count -> scan -> fill ----------------
__global__ void count_seg(const int* __restrict__ ei, const int* __restrict__ et,
                          int* __restrict__ segc)
{
    int e = blockIdx.x * blockDim.x + threadIdx.x;
    if (e < EE) {
        int dst = ei[EE + e];
        int r = et[e];
        atomicAdd(&segc[r * NN + dst], 1);
    }
}

// single-block exclusive scan over segc[NSEG] -> offs[NSEG+1]
__global__ __launch_bounds__(256) void scan_seg(const int* __restrict__ segc,
                                                int* __restrict__ offs)
{
    __shared__ int s_base;
    int lane = threadIdx.x & 63;
    int wave = threadIdx.x >> 6;
    __shared__ int wsum[4];
    if (threadIdx.x == 0) { s_base = 0; offs[0] = 0; }
    __syncthreads();
    for (int chunk = 0; chunk < NSEG; chunk += 256) {
        int i = chunk + threadIdx.x;
        int c = (i < NSEG) ? segc[i] : 0;
        // inclusive scan within wave
        int v = c;
#pragma unroll
        for (int off = 1; off < 64; off <<= 1) {
            int u = __shfl_up(v, off);
            if (lane >= off) v += u;
        }
        if (lane == 63) wsum[wave] = v;
        __syncthreads();
        int wadd = 0;
#pragma unroll
        for (int w = 0; w < 4; w++) if (w < wave) wadd += wsum[w];
        int incl = v + wadd + s_base;
        if (i < NSEG) offs[i + 1] = incl;
        __syncthreads();
        if (threadIdx.x == 255) s_base = incl;
        __syncthreads();
    }
}

__global__ void fill_src(const int* __restrict__ ei, const int* __restrict__ et,
                         const int* __restrict__ offs, int* __restrict__ cursor,
                         int* __restrict__ src_list)
{
    int e = blockIdx.x * blockDim.x + threadIdx.x;
    if (e < EE) {
        int src = ei[e];
        int dst = ei[EE + e];
        int s = et[e] * NN + dst;
        int pos = offs[s] + atomicAdd(&cursor[s], 1);
        src_list[pos] = src;
    }
}

// ---------------- gather: out[d,:] += sum_r mean_{e in seg(r,d)} hrel[r,src_e,:] ----
// one wave per dst node; out pre-initialized with h_root
__global__ __launch_bounds__(256) void gather_mean(
    const float* __restrict__ hrel,     // [2, N, HD]
    const int* __restrict__ offs,       // [NSEG+1]
    const int* __restrict__ src_list,   // [E]
    float* __restrict__ out)            // [N, HD]
{
    int d = blockIdx.x * 4 + (threadIdx.x >> 6);
    if (d >= NN) return;
    int lane = threadIdx.x & 63;
    float4 acc = {0.f, 0.f, 0.f, 0.f};
#pragma unroll
    for (int r = 0; r < 2; r++) {
        int s = r * NN + d;
        int start = offs[s], end = offs[s + 1];
        if (start == end) continue;
        float4 a = {0.f, 0.f, 0.f, 0.f};
        const float* base = hrel + (size_t)r * NN * HD;
        for (int i = start; i < end; i++) {
            int src = src_list[i];
            float4 v = ((const float4*)(base + (size_t)src * HD))[lane];
            a.x += v.x; a.y += v.y; a.z += v.z; a.w += v.w;
        }
        float inv = 1.0f / (float)(end - start);
        acc.x += a.x * inv; acc.y += a.y * inv;
        acc.z += a.z * inv; acc.w += a.w * inv;
    }
    float4* orow = (float4*)(out + (size_t)d * HD);
    float4 o = orow[lane];
    o.x += acc.x; o.y += acc.y; o.z += acc.z; o.w += acc.w;
    orow[lane] = o;
}

// ---------------- output head ----------------
__global__ __launch_bounds__(256) void out_proj(
    const float* __restrict__ x, const float* __restrict__ w,
    const float* __restrict__ b, float* __restrict__ out)
{
    int n = blockIdx.x * 4 + (threadIdx.x >> 6);
    if (n >= NN) return;
    int lane = threadIdx.x & 63;
    const float4* xr4 = (const float4*)(x + (size_t)n * HD);
    float4 v = xr4[lane];
    int k = lane * 4;
    float a0 = v.x * w[(k + 0) * 2 + 0] + v.y * w[(k + 1) * 2 + 0]
             + v.z * w[(k + 2) * 2 + 0] + v.w * w[(k + 3) * 2 + 0];
    float a1 = v.x * w[(k + 0) * 2 + 1] + v.y * w[(k + 1) * 2 + 1]
             + v.z * w[(k + 2) * 2 + 1] + v.w * w[(k + 3) * 2 + 1];
#pragma unroll
    for (int off = 32; off > 0; off >>= 1) {
        a0 += __shfl_down(a0, off);
        a1 += __shfl_down(a1, off);
    }
    if (lane == 0) {
        out[(size_t)n * 2 + 0] = a0 + b[0];
        out[(size_t)n * 2 + 1] = a1 + b[1];
    }
}

extern "C" void kernel_launch(void* const* d_in, const int* in_sizes, int n_in,
                              void* d_out, int out_size, void* d_ws, size_t ws_size,
                              hipStream_t stream)
{
    const float* des   = (const float*)d_in[0];
    const float* tweet = (const float*)d_in[1];
    const float* nump  = (const float*)d_in[2];
    const float* catp  = (const float*)d_in[3];
    const int*   ei    = (const int*)d_in[4];
    const int*   et    = (const int*)d_in[5];
    const float* w_des = (const float*)d_in[6],  *b_des = (const float*)d_in[7];
    const float* w_tw  = (const float*)d_in[8],  *b_tw  = (const float*)d_in[9];
    const float* w_num = (const float*)d_in[10], *b_num = (const float*)d_in[11];
    const float* w_cat = (const float*)d_in[12], *b_cat = (const float*)d_in[13];
    const float* w_in  = (const float*)d_in[14], *b_in  = (const float*)d_in[15];
    const float* weight1 = (const float*)d_in[16], *root1 = (const float*)d_in[17], *bias1 = (const float*)d_in[18];
    const float* weight2 = (const float*)d_in[19], *root2 = (const float*)d_in[20], *bias2 = (const float*)d_in[21];
    const float* w_out = (const float*)d_in[22], *b_out = (const float*)d_in[23];
    float* outp = (float*)d_out;

    // workspace carve-up:
    // x[N*HD] f32, y[N*HD] f32, hrel[2*N*HD] f32, offs[NSEG+1] i32,
    // segc[NSEG] i32 (counts, then reused as fill cursor), src_list[E] i32
    float* x    = (float*)d_ws;
    float* y    = x + (size_t)NN * HD;
    float* hrel = y + (size_t)NN * HD;
    int*   offs = (int*)(hrel + (size_t)2 * NN * HD);
    int*   segc = offs + (NSEG + 1);
    int*   srcl = segc + NSEG;

    // ---- CSR build (shared across both layers) ----
    hipMemsetAsync(segc, 0, NSEG * sizeof(int), stream);
    count_seg<<<(EE + 255) / 256, 256, 0, stream>>>(ei, et, segc);
    scan_seg<<<1, 256, 0, stream>>>(segc, offs);
    hipMemsetAsync(segc, 0, NSEG * sizeof(int), stream);
    fill_src<<<(EE + 255) / 256, 256, 0, stream>>>(ei, et, offs, segc, srcl);

    // ---- feature projections into columns of x (leaky relu) ----
    dim3 g64(1, (NN + 63) / 64);
    gemm_f32<64, 64, 16, 4, 4, 1><<<g64, 256, 0, stream>>>(des,   768, w_des, 64, b_des, x, HD, 0,   NN, 64, 768);
    gemm_f32<64, 64, 16, 4, 4, 1><<<g64, 256, 0, stream>>>(tweet, 768, w_tw,  64, b_tw,  x, HD, 64,  NN, 64, 768);
    gemm_f32<64, 64, 16, 4, 4, 1><<<g64, 256, 0, stream>>>(nump,  5,   w_num, 64, b_num, x, HD, 128, NN, 64, 5);
    gemm_f32<64, 64, 16, 4, 4, 1><<<g64, 256, 0, stream>>>(catp,  3,   w_cat, 64, b_cat, x, HD, 192, NN, 64, 3);

    // ---- x = lrelu(x @ w_in + b_in) -> y ----
    dim3 gbig(HD / 64, (NN + 127) / 128);
    gemm_f32<128, 64, 16, 8, 4, 1><<<gbig, 256, 0, stream>>>(x, HD, w_in, HD, b_in, y, HD, 0, NN, HD, HD);

    // ---- RGCN layer 1 ----
    gemm_f32<128, 64, 16, 8, 4, 2><<<gbig, 256, 0, stream>>>(y, HD, weight1,            HD, bias1, hrel,                    HD, 0, NN, HD, HD);
    gemm_f32<128, 64, 16, 8, 4, 2><<<gbig, 256, 0, stream>>>(y, HD, weight1 + HD * HD,  HD, bias1, hrel + (size_t)NN * HD,  HD, 0, NN, HD, HD);
    gemm_f32<128, 64, 16, 8, 4, 2><<<gbig, 256, 0, stream>>>(y, HD, root1,              HD, bias1, x,                       HD, 0, NN, HD, HD);
    gather_mean<<<(NN + 3) / 4, 256, 0, stream>>>(hrel, offs, srcl, x);

    // ---- RGCN layer 2 ----
    gemm_f32<128, 64, 16, 8, 4, 2><<<gbig, 256, 0, stream>>>(x, HD, weight2,            HD, bias2, hrel,                    HD, 0, NN, HD, HD);
    gemm_f32<128, 64, 16, 8, 4, 2><<<gbig, 256, 0, stream>>>(x, HD, weight2 + HD * HD,  HD, bias2, hrel + (size_t)NN * HD,  HD, 0, NN, HD, HD);
    gemm_f32<128, 64, 16, 8, 4, 2><<<gbig, 256, 0, stream>>>(x, HD, root2,              HD, bias2, y,                       HD, 0, NN, HD, HD);
    gather_mean<<<(NN + 3) / 4, 256, 0, stream>>>(hrel, offs, srcl, y);

    // ---- logits ----
    out_proj<<<(NN + 3) / 4, 256, 0, stream>>>(y, w_out, b_out, outp);
}

// Round 3
// 1511.786 us; speedup vs baseline: 2.0354x; 1.5410x over previous
//
#include <hip/hip_runtime.h>

#define NN 50000
#define EE 800000
#define HD 256
#define NSEG (2 * NN)
#define CHUNK 2048
#define NB ((NSEG + CHUNK - 1) / CHUNK)

// ---------------- GEMM: C[M,Ncol] = act(A[M,K] @ B[K,Ncol] + bias) ----------------
// ACT: 0=none, 1=leaky_relu(0.01), 2=relu
// VEC: vectorized float4 staging (requires K%4==0, lda%4==0, ldb rows 16B-aligned,
//      Ncol%BN==0, K<=lda)
template<int BM, int BN, int BK, int TM, int TN, int ACT, bool VEC>
__global__ __launch_bounds__(256) void gemm_f32(
    const float* __restrict__ A, int lda,
    const float* __restrict__ B, int ldb,
    const float* __restrict__ bias,
    float* __restrict__ C, int ldc, int coff,
    int M, int Ncol, int K)
{
    constexpr int TX = BN / TN;
    constexpr int TY = BM / TM;
    static_assert(TX * TY == 256, "thread grid must be 256");
    constexpr int PAD = 4;
    __shared__ float As[BK][BM + PAD];
    __shared__ float Bs[BK][BN + PAD];

    const int tid = threadIdx.x;
    const int tx = tid % TX, ty = tid / TX;
    const int brow = blockIdx.y * BM;
    const int bcol = blockIdx.x * BN;

    float acc[TM][TN];
#pragma unroll
    for (int i = 0; i < TM; i++)
#pragma unroll
        for (int j = 0; j < TN; j++) acc[i][j] = 0.f;

    for (int k0 = 0; k0 < K; k0 += BK) {
        if constexpr (VEC) {
            // A tile: BM x BK, float4 along k, transpose-store into As[k][m]
#pragma unroll
            for (int slot = tid; slot < BM * BK / 4; slot += 256) {
                int m = slot / (BK / 4);
                int k4 = (slot % (BK / 4)) * 4;
                int gr = brow + m;
                float4 v = {0.f, 0.f, 0.f, 0.f};
                if (gr < M) v = *(const float4*)&A[(size_t)gr * lda + k0 + k4];
                As[k4 + 0][m] = v.x; As[k4 + 1][m] = v.y;
                As[k4 + 2][m] = v.z; As[k4 + 3][m] = v.w;
            }
            // B tile: BK x BN, float4 along n, natural row-major
#pragma unroll
            for (int slot = tid; slot < BK * BN / 4; slot += 256) {
                int k = slot / (BN / 4);
                int n4 = (slot % (BN / 4)) * 4;
                *(float4*)&Bs[k][n4] =
                    *(const float4*)&B[(size_t)(k0 + k) * ldb + bcol + n4];
            }
        } else {
#pragma unroll
            for (int idx = tid; idx < BM * BK; idx += 256) {
                int m = idx / BK, k = idx % BK;
                int gr = brow + m, gk = k0 + k;
                As[k][m] = (gr < M && gk < K) ? A[(size_t)gr * lda + gk] : 0.f;
            }
#pragma unroll
            for (int idx = tid; idx < BK * BN; idx += 256) {
                int k = idx / BN, n = idx % BN;
                int gk = k0 + k, gc = bcol + n;
                Bs[k][n] = (gk < K && gc < Ncol) ? B[(size_t)gk * ldb + gc] : 0.f;
            }
        }
        __syncthreads();
#pragma unroll
        for (int k = 0; k < BK; k++) {
            float a[TM], b[TN];
#pragma unroll
            for (int i4 = 0; i4 < TM; i4 += 4)
                *(float4*)&a[i4] = *(float4*)&As[k][ty * TM + i4];
            if constexpr (TN == 8) {
                // split-column fragment: banks 4*tx -> <=2-way alias (free)
                *(float4*)&b[0] = *(float4*)&Bs[k][tx * 4];
                *(float4*)&b[4] = *(float4*)&Bs[k][BN / 2 + tx * 4];
            } else {
                *(float4*)&b[0] = *(float4*)&Bs[k][tx * TN];
            }
#pragma unroll
            for (int i = 0; i < TM; i++)
#pragma unroll
                for (int j = 0; j < TN; j++) acc[i][j] = fmaf(a[i], b[j], acc[i][j]);
        }
        __syncthreads();
    }

#pragma unroll
    for (int i = 0; i < TM; i++) {
        int gr = brow + ty * TM + i;
        if (gr >= M) continue;
#pragma unroll
        for (int j = 0; j < TN; j++) {
            int gc;
            if constexpr (TN == 8)
                gc = bcol + ((j < 4) ? (tx * 4 + j) : (BN / 2 + tx * 4 + (j - 4)));
            else
                gc = bcol + tx * TN + j;
            if (gc >= Ncol) continue;
            float v = acc[i][j] + bias[gc];
            if (ACT == 1) v = v > 0.f ? v : 0.01f * v;
            else if (ACT == 2) v = fmaxf(v, 0.f);
            C[(size_t)gr * ldc + coff + gc] = v;
        }
    }
}

// ---------------- CSR build: count -> hierarchical scan -> fill ----------------
__global__ void count_seg(const int* __restrict__ ei, const int* __restrict__ et,
                          int* __restrict__ segc)
{
    int e = blockIdx.x * blockDim.x + threadIdx.x;
    if (e < EE) {
        int dst = ei[EE + e];
        int r = et[e];
        atomicAdd(&segc[r * NN + dst], 1);
    }
}

// pass 1: per-block local inclusive scan of CHUNK elems + block sum
__global__ __launch_bounds__(256) void scan_local(const int* __restrict__ segc,
                                                  int* __restrict__ offs,
                                                  int* __restrict__ bsum)
{
    int b = blockIdx.x;
    int base = b * CHUNK;
    int tid = threadIdx.x;
    int lane = tid & 63, wave = tid >> 6;
    __shared__ int wsum[4];

    int vals[8];
    int i0 = base + tid * 8;
    int s = 0;
    if (i0 + 7 < NSEG) {
        int4 v0 = *(const int4*)&segc[i0];
        int4 v1 = *(const int4*)&segc[i0 + 4];
        vals[0] = v0.x; vals[1] = v0.y; vals[2] = v0.z; vals[3] = v0.w;
        vals[4] = v1.x; vals[5] = v1.y; vals[6] = v1.z; vals[7] = v1.w;
    } else {
#pragma unroll
        for (int j = 0; j < 8; j++) vals[j] = (i0 + j < NSEG) ? segc[i0 + j] : 0;
    }
#pragma unroll
    for (int j = 0; j < 8; j++) s += vals[j];

    // wave inclusive scan of thread sums
    int v = s;
#pragma unroll
    for (int off = 1; off < 64; off <<= 1) {
        int u = __shfl_up(v, off);
        if (lane >= off) v += u;
    }
    if (lane == 63) wsum[wave] = v;
    __syncthreads();
    int wbase = 0;
#pragma unroll
    for (int w = 0; w < 4; w++) if (w < wave) wbase += wsum[w];
    int run = wbase + v - s;   // exclusive prefix of this thread within block
#pragma unroll
    for (int j = 0; j < 8; j++) {
        run += vals[j];
        int i = i0 + j;
        if (i < NSEG) offs[i + 1] = run;   // local inclusive; block base added later
    }
    if (tid == 0) {
        int t = 0;
#pragma unroll
        for (int w = 0; w < 4; w++) t += wsum[w];
        bsum[b] = t;
    }
}

// pass 2: exclusive scan of the NB block sums (one wave)
__global__ void scan_bsum(const int* __restrict__ bsum, int* __restrict__ bbase)
{
    int lane = threadIdx.x;
    int c = (lane < NB) ? bsum[lane] : 0;
    int v = c;
#pragma unroll
    for (int off = 1; off < 64; off <<= 1) {
        int u = __shfl_up(v, off);
        if (lane >= off) v += u;
    }
    if (lane < NB) bbase[lane] = v - c;
}

// pass 3: add block bases; set offs[0]
__global__ void add_base(int* __restrict__ offs, const int* __restrict__ bbase)
{
    int i = blockIdx.x * blockDim.x + threadIdx.x;
    if (i < NSEG) offs[i + 1] += bbase[i / CHUNK];
    if (i == 0) offs[0] = 0;
}

__global__ void fill_src(const int* __restrict__ ei, const int* __restrict__ et,
                         const int* __restrict__ offs, int* __restrict__ cursor,
                         int* __restrict__ src_list)
{
    int e = blockIdx.x * blockDim.x + threadIdx.x;
    if (e < EE) {
        int src = ei[e];
        int dst = ei[EE + e];
        int s = et[e] * NN + dst;
        int pos = offs[s] + atomicAdd(&cursor[s], 1);
        src_list[pos] = src;
    }
}

// ---------------- gather: out[d,:] += sum_r mean_{e in seg(r,d)} hrel[r,src_e,:] ----
__global__ __launch_bounds__(256) void gather_mean(
    const float* __restrict__ hrel,     // [2, N, HD]
    const int* __restrict__ offs,       // [NSEG+1]
    const int* __restrict__ src_list,   // [E]
    float* __restrict__ out)            // [N, HD], pre-initialized with h_root
{
    int d = blockIdx.x * 4 + (threadIdx.x >> 6);
    if (d >= NN) return;
    int lane = threadIdx.x & 63;
    float4 acc = {0.f, 0.f, 0.f, 0.f};
#pragma unroll
    for (int r = 0; r < 2; r++) {
        int s = r * NN + d;
        int start = offs[s], end = offs[s + 1];
        if (start == end) continue;
        float4 a = {0.f, 0.f, 0.f, 0.f};
        const float* base = hrel + (size_t)r * NN * HD;
        for (int i = start; i < end; i++) {
            int src = src_list[i];
            float4 v = ((const float4*)(base + (size_t)src * HD))[lane];
            a.x += v.x; a.y += v.y; a.z += v.z; a.w += v.w;
        }
        float inv = 1.0f / (float)(end - start);
        acc.x += a.x * inv; acc.y += a.y * inv;
        acc.z += a.z * inv; acc.w += a.w * inv;
    }
    float4* orow = (float4*)(out + (size_t)d * HD);
    float4 o = orow[lane];
    o.x += acc.x; o.y += acc.y; o.z += acc.z; o.w += acc.w;
    orow[lane] = o;
}

// ---------------- output head ----------------
__global__ __launch_bounds__(256) void out_proj(
    const float* __restrict__ x, const float* __restrict__ w,
    const float* __restrict__ b, float* __restrict__ out)
{
    int n = blockIdx.x * 4 + (threadIdx.x >> 6);
    if (n >= NN) return;
    int lane = threadIdx.x & 63;
    const float4* xr4 = (const float4*)(x + (size_t)n * HD);
    float4 v = xr4[lane];
    int k = lane * 4;
    float a0 = v.x * w[(k + 0) * 2 + 0] + v.y * w[(k + 1) * 2 + 0]
             + v.z * w[(k + 2) * 2 + 0] + v.w * w[(k + 3) * 2 + 0];
    float a1 = v.x * w[(k + 0) * 2 + 1] + v.y * w[(k + 1) * 2 + 1]
             + v.z * w[(k + 2) * 2 + 1] + v.w * w[(k + 3) * 2 + 1];
#pragma unroll
    for (int off = 32; off > 0; off >>= 1) {
        a0 += __shfl_down(a0, off);
        a1 += __shfl_down(a1, off);
    }
    if (lane == 0) {
        out[(size_t)n * 2 + 0] = a0 + b[0];
        out[(size_t)n * 2 + 1] = a1 + b[1];
    }
}

extern "C" void kernel_launch(void* const* d_in, const int* in_sizes, int n_in,
                              void* d_out, int out_size, void* d_ws, size_t ws_size,
                              hipStream_t stream)
{
    const float* des   = (const float*)d_in[0];
    const float* tweet = (const float*)d_in[1];
    const float* nump  = (const float*)d_in[2];
    const float* catp  = (const float*)d_in[3];
    const int*   ei    = (const int*)d_in[4];
    const int*   et    = (const int*)d_in[5];
    const float* w_des = (const float*)d_in[6],  *b_des = (const float*)d_in[7];
    const float* w_tw  = (const float*)d_in[8],  *b_tw  = (const float*)d_in[9];
    const float* w_num = (const float*)d_in[10], *b_num = (const float*)d_in[11];
    const float* w_cat = (const float*)d_in[12], *b_cat = (const float*)d_in[13];
    const float* w_in  = (const float*)d_in[14], *b_in  = (const float*)d_in[15];
    const float* weight1 = (const float*)d_in[16], *root1 = (const float*)d_in[17], *bias1 = (const float*)d_in[18];
    const float* weight2 = (const float*)d_in[19], *root2 = (const float*)d_in[20], *bias2 = (const float*)d_in[21];
    const float* w_out = (const float*)d_in[22], *b_out = (const float*)d_in[23];
    float* outp = (float*)d_out;

    // workspace: x[N*HD] f32, y[N*HD] f32, hrel[2*N*HD] f32,
    // offs[NSEG+1], segc[NSEG] (counts then cursor), src_list[E], bsum[NB], bbase[NB]
    float* x    = (float*)d_ws;
    float* y    = x + (size_t)NN * HD;
    float* hrel = y + (size_t)NN * HD;
    int*   offs = (int*)(hrel + (size_t)2 * NN * HD);
    int*   segc = offs + (NSEG + 1);
    int*   srcl = segc + NSEG;
    int*   bsum = srcl + EE;
    int*   bbase = bsum + NB;

    // ---- CSR build (shared across both layers) ----
    hipMemsetAsync(segc, 0, NSEG * sizeof(int), stream);
    count_seg<<<(EE + 255) / 256, 256, 0, stream>>>(ei, et, segc);
    scan_local<<<NB, 256, 0, stream>>>(segc, offs, bsum);
    scan_bsum<<<1, 64, 0, stream>>>(bsum, bbase);
    add_base<<<(NSEG + 255) / 256, 256, 0, stream>>>(offs, bbase);
    hipMemsetAsync(segc, 0, NSEG * sizeof(int), stream);
    fill_src<<<(EE + 255) / 256, 256, 0, stream>>>(ei, et, offs, segc, srcl);

    // ---- feature projections into columns of x (leaky relu) ----
    dim3 gproj(1, (NN + 127) / 128);
    gemm_f32<128, 64, 16, 8, 4, 1, true ><<<gproj, 256, 0, stream>>>(des,   768, w_des, 64, b_des, x, HD, 0,   NN, 64, 768);
    gemm_f32<128, 64, 16, 8, 4, 1, true ><<<gproj, 256, 0, stream>>>(tweet, 768, w_tw,  64, b_tw,  x, HD, 64,  NN, 64, 768);
    dim3 gsmall(1, (NN + 63) / 64);
    gemm_f32<64, 64, 16, 4, 4, 1, false><<<gsmall, 256, 0, stream>>>(nump,  5,   w_num, 64, b_num, x, HD, 128, NN, 64, 5);
    gemm_f32<64, 64, 16, 4, 4, 1, false><<<gsmall, 256, 0, stream>>>(catp,  3,   w_cat, 64, b_cat, x, HD, 192, NN, 64, 3);

    // ---- x = lrelu(x @ w_in + b_in) -> y ----
    dim3 gbig(HD / 128, (NN + 127) / 128);
    gemm_f32<128, 128, 16, 8, 8, 1, true><<<gbig, 256, 0, stream>>>(x, HD, w_in, HD, b_in, y, HD, 0, NN, HD, HD);

    // ---- RGCN layer 1 ----
    gemm_f32<128, 128, 16, 8, 8, 2, true><<<gbig, 256, 0, stream>>>(y, HD, weight1,           HD, bias1, hrel,                   HD, 0, NN, HD, HD);
    gemm_f32<128, 128, 16, 8, 8, 2, true><<<gbig, 256, 0, stream>>>(y, HD, weight1 + HD * HD, HD, bias1, hrel + (size_t)NN * HD, HD, 0, NN, HD, HD);
    gemm_f32<128, 128, 16, 8, 8, 2, true><<<gbig, 256, 0, stream>>>(y, HD, root1,             HD, bias1, x,                      HD, 0, NN, HD, HD);
    gather_mean<<<(NN + 3) / 4, 256, 0, stream>>>(hrel, offs, srcl, x);

    // ---- RGCN layer 2 ----
    gemm_f32<128, 128, 16, 8, 8, 2, true><<<gbig, 256, 0, stream>>>(x, HD, weight2,           HD, bias2, hrel,                   HD, 0, NN, HD, HD);
    gemm_f32<128, 128, 16, 8, 8, 2, true><<<gbig, 256, 0, stream>>>(x, HD, weight2 + HD * HD, HD, bias2, hrel + (size_t)NN * HD, HD, 0, NN, HD, HD);
    gemm_f32<128, 128, 16, 8, 8, 2, true><<<gbig, 256, 0, stream>>>(x, HD, root2,             HD, bias2, y,                      HD, 0, NN, HD, HD);
    gather_mean<<<(NN + 3) / 4, 256, 0, stream>>>(hrel, offs, srcl, y);

    // ---- logits ----
    out_proj<<<(NN + 3) / 4, 256, 0, stream>>>(y, w_out, b_out, outp);
}

// Round 4
// 1009.421 us; speedup vs baseline: 3.0483x; 1.4977x over previous
//
#include <hip/hip_runtime.h>

#define NN 50000
#define EE 800000
#define HD 256
#define NSEG (2 * NN)
#define CHUNK 2048
#define NB ((NSEG + CHUNK - 1) / CHUNK)

typedef short bf16x8 __attribute__((ext_vector_type(8)));
typedef float f32x4 __attribute__((ext_vector_type(4)));

__device__ __forceinline__ unsigned short f2bf(float f) {
    unsigned u = __float_as_uint(f);
    return (unsigned short)((u + 0x7FFF + ((u >> 16) & 1)) >> 16);
}
__device__ __forceinline__ float bf2f(unsigned short h) {
    return __uint_as_float(((unsigned)h) << 16);
}

// ============ MFMA GEMM: C = act(A_f32 @ B + bias), B pre-split bf16 hi/lo ============
// A: f32 [M][lda], split to hi/lo during LDS staging.
// Bh/Bl: bf16 [Ncol][K] (transposed, k-contiguous).
// acc = Ah*Bh + Al*Bh + Ah*Bl  (missing Al*Bl term ~2^-18 relative).
// 4 waves in 2x2 grid; MFMA 16x16x32; LDS tiles in fragment-major order:
//   tile[(g*BMorBN + row_or_col)*8 + j] holds elem k = k0 + g*8 + j  (g = lane>>4).
// ACT: 0=none, 1=leaky_relu(0.01), 2=relu
template<int BM, int BN, int ACT>
__global__ __launch_bounds__(256) void gemm_mfma(
    const float* __restrict__ A, int lda,
    const unsigned short* __restrict__ Bh,
    const unsigned short* __restrict__ Bl,
    const float* __restrict__ bias,
    float* __restrict__ C, int ldc, int coff,
    int M, int K)
{
    constexpr int WM = BM / 2, WN = BN / 2;
    constexpr int MI = WM / 16, NI = WN / 16;
    constexpr int APT = (BM * 8) / 256;   // float4 slots per thread (A tile)
    constexpr int BPT = (BN * 4) / 256;   // 16B slots per thread (B tile)

    __shared__ __align__(16) unsigned short Ah[4 * BM * 8];
    __shared__ __align__(16) unsigned short Al[4 * BM * 8];
    __shared__ __align__(16) unsigned short Bsh[4 * BN * 8];
    __shared__ __align__(16) unsigned short Bsl[4 * BN * 8];

    const int tid = threadIdx.x;
    const int lane = tid & 63;
    const int w = tid >> 6;
    const int wr = w >> 1, wc = w & 1;
    const int brow = blockIdx.y * BM, bcol = blockIdx.x * BN;
    const int r15 = lane & 15, g = lane >> 4;

    f32x4 acc[MI][NI];
#pragma unroll
    for (int mi = 0; mi < MI; mi++)
#pragma unroll
        for (int ni = 0; ni < NI; ni++) acc[mi][ni] = (f32x4){0.f, 0.f, 0.f, 0.f};

    for (int k0 = 0; k0 < K; k0 += 32) {
        // ---- A stage: f32 -> hi/lo bf16, fragment-major ----
#pragma unroll
        for (int s = 0; s < APT; s++) {
            int slot = tid + s * 256;
            int row = slot >> 3, k4 = (slot & 7) * 4;
            float4 v = {0.f, 0.f, 0.f, 0.f};
            int gr = brow + row;
            if (gr < M) v = *(const float4*)&A[(size_t)gr * lda + k0 + k4];
            float vf[4] = {v.x, v.y, v.z, v.w};
            unsigned long long ph = 0, pl = 0;
#pragma unroll
            for (int j = 0; j < 4; j++) {
                unsigned short h = f2bf(vf[j]);
                unsigned short l = f2bf(vf[j] - bf2f(h));
                ph |= ((unsigned long long)h) << (16 * j);
                pl |= ((unsigned long long)l) << (16 * j);
            }
            int base = ((k4 >> 3) * BM + row) * 8 + (k4 & 7);
            *(unsigned long long*)&Ah[base] = ph;
            *(unsigned long long*)&Al[base] = pl;
        }
        // ---- B stage: copy pre-split bf16 (16B per slot) ----
#pragma unroll
        for (int s = 0; s < BPT; s++) {
            int slot = tid + s * 256;
            int col = slot & (BN - 1), gg = slot / BN;
            size_t off = (size_t)(bcol + col) * K + k0 + gg * 8;
            *(uint4*)&Bsh[slot * 8] = *(const uint4*)&Bh[off];
            *(uint4*)&Bsl[slot * 8] = *(const uint4*)&Bl[off];
        }
        __syncthreads();

        bf16x8 afh[MI], afl[MI], bfh[NI], bfl[NI];
#pragma unroll
        for (int mi = 0; mi < MI; mi++) {
            int idx = (g * BM + wr * WM + mi * 16 + r15) * 8;
            afh[mi] = *(const bf16x8*)&Ah[idx];
            afl[mi] = *(const bf16x8*)&Al[idx];
        }
#pragma unroll
        for (int ni = 0; ni < NI; ni++) {
            int idx = (g * BN + wc * WN + ni * 16 + r15) * 8;
            bfh[ni] = *(const bf16x8*)&Bsh[idx];
            bfl[ni] = *(const bf16x8*)&Bsl[idx];
        }
#pragma unroll
        for (int mi = 0; mi < MI; mi++)
#pragma unroll
            for (int ni = 0; ni < NI; ni++)
                acc[mi][ni] = __builtin_amdgcn_mfma_f32_16x16x32_bf16(afh[mi], bfh[ni], acc[mi][ni], 0, 0, 0);
#pragma unroll
        for (int mi = 0; mi < MI; mi++)
#pragma unroll
            for (int ni = 0; ni < NI; ni++)
                acc[mi][ni] = __builtin_amdgcn_mfma_f32_16x16x32_bf16(afl[mi], bfh[ni], acc[mi][ni], 0, 0, 0);
#pragma unroll
        for (int mi = 0; mi < MI; mi++)
#pragma unroll
            for (int ni = 0; ni < NI; ni++)
                acc[mi][ni] = __builtin_amdgcn_mfma_f32_16x16x32_bf16(afh[mi], bfl[ni], acc[mi][ni], 0, 0, 0);
        __syncthreads();
    }

    // ---- epilogue: C/D layout col=lane&15, row=(lane>>4)*4+reg ----
#pragma unroll
    for (int mi = 0; mi < MI; mi++) {
#pragma unroll
        for (int ni = 0; ni < NI; ni++) {
            int col = bcol + wc * WN + ni * 16 + r15;
            float bsv = bias[col];
            int rbase = brow + wr * WM + mi * 16 + g * 4;
#pragma unroll
            for (int r = 0; r < 4; r++) {
                int grow = rbase + r;
                if (grow >= M) continue;
                float v = acc[mi][ni][r] + bsv;
                if (ACT == 1) v = v > 0.f ? v : 0.01f * v;
                else if (ACT == 2) v = fmaxf(v, 0.f);
                C[(size_t)grow * ldc + coff + col] = v;
            }
        }
    }
}

// ---- weight split+transpose: W f32 [K][Ncol] -> Th/Tl bf16 [Ncol][K] ----
__global__ void conv_w(const float* __restrict__ W, int K, int Ncol,
                       unsigned short* __restrict__ Th, unsigned short* __restrict__ Tl)
{
    int i = blockIdx.x * 256 + threadIdx.x;
    if (i >= K * Ncol) return;
    int k = i / Ncol, n = i % Ncol;
    float v = W[i];
    unsigned short h = f2bf(v);
    Th[(size_t)n * K + k] = h;
    Tl[(size_t)n * K + k] = f2bf(v - bf2f(h));
}

// ---------------- small f32 GEMM (K=5/3 feature projections) ----------------
template<int BM, int BN, int BK, int TM, int TN>
__global__ __launch_bounds__(256) void gemm_f32s(
    const float* __restrict__ A, int lda,
    const float* __restrict__ B, int ldb,
    const float* __restrict__ bias,
    float* __restrict__ C, int ldc, int coff,
    int M, int Ncol, int K)
{
    constexpr int TX = BN / TN;
    __shared__ float As[BK][BM + 4];
    __shared__ float Bs[BK][BN + 4];
    const int tid = threadIdx.x;
    const int tx = tid % TX, ty = tid / TX;
    const int brow = blockIdx.y * BM;
    const int bcol = blockIdx.x * BN;
    float acc[TM][TN];
#pragma unroll
    for (int i = 0; i < TM; i++)
#pragma unroll
        for (int j = 0; j < TN; j++) acc[i][j] = 0.f;
    for (int k0 = 0; k0 < K; k0 += BK) {
#pragma unroll
        for (int idx = tid; idx < BM * BK; idx += 256) {
            int m = idx / BK, k = idx % BK;
            int gr = brow + m, gk = k0 + k;
            As[k][m] = (gr < M && gk < K) ? A[(size_t)gr * lda + gk] : 0.f;
        }
#pragma unroll
        for (int idx = tid; idx < BK * BN; idx += 256) {
            int k = idx / BN, n = idx % BN;
            int gk = k0 + k, gc = bcol + n;
            Bs[k][n] = (gk < K && gc < Ncol) ? B[(size_t)gk * ldb + gc] : 0.f;
        }
        __syncthreads();
#pragma unroll
        for (int k = 0; k < BK; k++) {
            float a[TM], b[TN];
#pragma unroll
            for (int i = 0; i < TM; i++) a[i] = As[k][ty * TM + i];
#pragma unroll
            for (int j = 0; j < TN; j++) b[j] = Bs[k][tx * TN + j];
#pragma unroll
            for (int i = 0; i < TM; i++)
#pragma unroll
                for (int j = 0; j < TN; j++) acc[i][j] = fmaf(a[i], b[j], acc[i][j]);
        }
        __syncthreads();
    }
#pragma unroll
    for (int i = 0; i < TM; i++) {
        int gr = brow + ty * TM + i;
        if (gr >= M) continue;
#pragma unroll
        for (int j = 0; j < TN; j++) {
            int gc = bcol + tx * TN + j;
            if (gc >= Ncol) continue;
            float v = acc[i][j] + bias[gc];
            v = v > 0.f ? v : 0.01f * v;   // leaky relu
            C[(size_t)gr * ldc + coff + gc] = v;
        }
    }
}

// ---------------- CSR build: count -> hierarchical scan -> fill ----------------
__global__ void count_seg(const int* __restrict__ ei, const int* __restrict__ et,
                          int* __restrict__ segc)
{
    int e = blockIdx.x * blockDim.x + threadIdx.x;
    if (e < EE) {
        int dst = ei[EE + e];
        int r = et[e];
        atomicAdd(&segc[r * NN + dst], 1);
    }
}

__global__ __launch_bounds__(256) void scan_local(const int* __restrict__ segc,
                                                  int* __restrict__ offs,
                                                  int* __restrict__ bsum)
{
    int b = blockIdx.x;
    int base = b * CHUNK;
    int tid = threadIdx.x;
    int lane = tid & 63, wave = tid >> 6;
    __shared__ int wsum[4];
    int vals[8];
    int i0 = base + tid * 8;
    int s = 0;
    if (i0 + 7 < NSEG) {
        int4 v0 = *(const int4*)&segc[i0];
        int4 v1 = *(const int4*)&segc[i0 + 4];
        vals[0] = v0.x; vals[1] = v0.y; vals[2] = v0.z; vals[3] = v0.w;
        vals[4] = v1.x; vals[5] = v1.y; vals[6] = v1.z; vals[7] = v1.w;
    } else {
#pragma unroll
        for (int j = 0; j < 8; j++) vals[j] = (i0 + j < NSEG) ? segc[i0 + j] : 0;
    }
#pragma unroll
    for (int j = 0; j < 8; j++) s += vals[j];
    int v = s;
#pragma unroll
    for (int off = 1; off < 64; off <<= 1) {
        int u = __shfl_up(v, off);
        if (lane >= off) v += u;
    }
    if (lane == 63) wsum[wave] = v;
    __syncthreads();
    int wbase = 0;
#pragma unroll
    for (int ww = 0; ww < 4; ww++) if (ww < wave) wbase += wsum[ww];
    int run = wbase + v - s;
#pragma unroll
    for (int j = 0; j < 8; j++) {
        run += vals[j];
        int i = i0 + j;
        if (i < NSEG) offs[i + 1] = run;
    }
    if (tid == 0) {
        int t = 0;
#pragma unroll
        for (int ww = 0; ww < 4; ww++) t += wsum[ww];
        bsum[b] = t;
    }
}

__global__ void scan_bsum(const int* __restrict__ bsum, int* __restrict__ bbase)
{
    int lane = threadIdx.x;
    int c = (lane < NB) ? bsum[lane] : 0;
    int v = c;
#pragma unroll
    for (int off = 1; off < 64; off <<= 1) {
        int u = __shfl_up(v, off);
        if (lane >= off) v += u;
    }
    if (lane < NB) bbase[lane] = v - c;
}

__global__ void add_base(int* __restrict__ offs, const int* __restrict__ bbase)
{
    int i = blockIdx.x * blockDim.x + threadIdx.x;
    if (i < NSEG) offs[i + 1] += bbase[i / CHUNK];
    if (i == 0) offs[0] = 0;
}

__global__ void fill_src(const int* __restrict__ ei, const int* __restrict__ et,
                         const int* __restrict__ offs, int* __restrict__ cursor,
                         int* __restrict__ src_list)
{
    int e = blockIdx.x * blockDim.x + threadIdx.x;
    if (e < EE) {
        int src = ei[e];
        int dst = ei[EE + e];
        int s = et[e] * NN + dst;
        int pos = offs[s] + atomicAdd(&cursor[s], 1);
        src_list[pos] = src;
    }
}

// ---------------- gather: out[d,:] += sum_r mean_{e in seg(r,d)} hrel[r,src_e,:] ----
__global__ __launch_bounds__(256) void gather_mean(
    const float* __restrict__ hrel,
    const int* __restrict__ offs,
    const int* __restrict__ src_list,
    float* __restrict__ out)
{
    int d = blockIdx.x * 4 + (threadIdx.x >> 6);
    if (d >= NN) return;
    int lane = threadIdx.x & 63;
    float4 acc = {0.f, 0.f, 0.f, 0.f};
#pragma unroll
    for (int r = 0; r < 2; r++) {
        int s = r * NN + d;
        int start = offs[s], end = offs[s + 1];
        if (start == end) continue;
        float4 a = {0.f, 0.f, 0.f, 0.f};
        const float* base = hrel + (size_t)r * NN * HD;
        for (int i = start; i < end; i++) {
            int src = src_list[i];
            float4 v = ((const float4*)(base + (size_t)src * HD))[lane];
            a.x += v.x; a.y += v.y; a.z += v.z; a.w += v.w;
        }
        float inv = 1.0f / (float)(end - start);
        acc.x += a.x * inv; acc.y += a.y * inv;
        acc.z += a.z * inv; acc.w += a.w * inv;
    }
    float4* orow = (float4*)(out + (size_t)d * HD);
    float4 o = orow[lane];
    o.x += acc.x; o.y += acc.y; o.z += acc.z; o.w += acc.w;
    orow[lane] = o;
}

// ---------------- output head ----------------
__global__ __launch_bounds__(256) void out_proj(
    const float* __restrict__ x, const float* __restrict__ w,
    const float* __restrict__ b, float* __restrict__ out)
{
    int n = blockIdx.x * 4 + (threadIdx.x >> 6);
    if (n >= NN) return;
    int lane = threadIdx.x & 63;
    const float4* xr4 = (const float4*)(x + (size_t)n * HD);
    float4 v = xr4[lane];
    int k = lane * 4;
    float a0 = v.x * w[(k + 0) * 2 + 0] + v.y * w[(k + 1) * 2 + 0]
             + v.z * w[(k + 2) * 2 + 0] + v.w * w[(k + 3) * 2 + 0];
    float a1 = v.x * w[(k + 0) * 2 + 1] + v.y * w[(k + 1) * 2 + 1]
             + v.z * w[(k + 2) * 2 + 1] + v.w * w[(k + 3) * 2 + 1];
#pragma unroll
    for (int off = 32; off > 0; off >>= 1) {
        a0 += __shfl_down(a0, off);
        a1 += __shfl_down(a1, off);
    }
    if (lane == 0) {
        out[(size_t)n * 2 + 0] = a0 + b[0];
        out[(size_t)n * 2 + 1] = a1 + b[1];
    }
}

extern "C" void kernel_launch(void* const* d_in, const int* in_sizes, int n_in,
                              void* d_out, int out_size, void* d_ws, size_t ws_size,
                              hipStream_t stream)
{
    const float* des   = (const float*)d_in[0];
    const float* tweet = (const float*)d_in[1];
    const float* nump  = (const float*)d_in[2];
    const float* catp  = (const float*)d_in[3];
    const int*   ei    = (const int*)d_in[4];
    const int*   et    = (const int*)d_in[5];
    const float* w_des = (const float*)d_in[6],  *b_des = (const float*)d_in[7];
    const float* w_tw  = (const float*)d_in[8],  *b_tw  = (const float*)d_in[9];
    const float* w_num = (const float*)d_in[10], *b_num = (const float*)d_in[11];
    const float* w_cat = (const float*)d_in[12], *b_cat = (const float*)d_in[13];
    const float* w_in  = (const float*)d_in[14], *b_in  = (const float*)d_in[15];
    const float* weight1 = (const float*)d_in[16], *root1 = (const float*)d_in[17], *bias1 = (const float*)d_in[18];
    const float* weight2 = (const float*)d_in[19], *root2 = (const float*)d_in[20], *bias2 = (const float*)d_in[21];
    const float* w_out = (const float*)d_in[22], *b_out = (const float*)d_in[23];
    float* outp = (float*)d_out;

    // workspace: x, y, hrel (f32), CSR ints, then bf16 weight buffers
    float* x    = (float*)d_ws;
    float* y    = x + (size_t)NN * HD;
    float* hrel = y + (size_t)NN * HD;
    int*   offs = (int*)(hrel + (size_t)2 * NN * HD);
    int*   segc = offs + (NSEG + 1);
    int*   srcl = segc + NSEG;
    int*   bsum = srcl + EE;
    int*   bbase = bsum + NB;
    uintptr_t wp = ((uintptr_t)(bbase + NB) + 15) & ~(uintptr_t)15;
    unsigned short* wb = (unsigned short*)wp;
    const int PSZ = 768 * 64, HSZ = HD * HD;
    unsigned short *des_h = wb,          *des_l = des_h + PSZ;
    unsigned short *tw_h  = des_l + PSZ, *tw_l  = tw_h + PSZ;
    unsigned short *win_h = tw_l + PSZ,  *win_l = win_h + HSZ;
    unsigned short *w1ah = win_l + HSZ,  *w1al = w1ah + HSZ;
    unsigned short *w1bh = w1al + HSZ,   *w1bl = w1bh + HSZ;
    unsigned short *r1h  = w1bl + HSZ,   *r1l  = r1h + HSZ;
    unsigned short *w2ah = r1l + HSZ,    *w2al = w2ah + HSZ;
    unsigned short *w2bh = w2al + HSZ,   *w2bl = w2bh + HSZ;
    unsigned short *r2h  = w2bl + HSZ,   *r2l  = r2h + HSZ;

    // ---- CSR build ----
    hipMemsetAsync(segc, 0, NSEG * sizeof(int), stream);
    count_seg<<<(EE + 255) / 256, 256, 0, stream>>>(ei, et, segc);
    scan_local<<<NB, 256, 0, stream>>>(segc, offs, bsum);
    scan_bsum<<<1, 64, 0, stream>>>(bsum, bbase);
    add_base<<<(NSEG + 255) / 256, 256, 0, stream>>>(offs, bbase);
    hipMemsetAsync(segc, 0, NSEG * sizeof(int), stream);
    fill_src<<<(EE + 255) / 256, 256, 0, stream>>>(ei, et, offs, segc, srcl);

    // ---- weight split+transpose ----
    conv_w<<<(PSZ + 255) / 256, 256, 0, stream>>>(w_des, 768, 64, des_h, des_l);
    conv_w<<<(PSZ + 255) / 256, 256, 0, stream>>>(w_tw,  768, 64, tw_h,  tw_l);
    conv_w<<<(HSZ + 255) / 256, 256, 0, stream>>>(w_in, HD, HD, win_h, win_l);
    conv_w<<<(HSZ + 255) / 256, 256, 0, stream>>>(weight1,           HD, HD, w1ah, w1al);
    conv_w<<<(HSZ + 255) / 256, 256, 0, stream>>>(weight1 + HSZ,     HD, HD, w1bh, w1bl);
    conv_w<<<(HSZ + 255) / 256, 256, 0, stream>>>(root1,             HD, HD, r1h,  r1l);
    conv_w<<<(HSZ + 255) / 256, 256, 0, stream>>>(weight2,           HD, HD, w2ah, w2al);
    conv_w<<<(HSZ + 255) / 256, 256, 0, stream>>>(weight2 + HSZ,     HD, HD, w2bh, w2bl);
    conv_w<<<(HSZ + 255) / 256, 256, 0, stream>>>(root2,             HD, HD, r2h,  r2l);

    // ---- feature projections (leaky relu) ----
    dim3 gproj(1, (NN + 127) / 128);
    gemm_mfma<128, 64, 1><<<gproj, 256, 0, stream>>>(des,   768, des_h, des_l, b_des, x, HD, 0,  NN, 768);
    gemm_mfma<128, 64, 1><<<gproj, 256, 0, stream>>>(tweet, 768, tw_h,  tw_l,  b_tw,  x, HD, 64, NN, 768);
    dim3 gsmall(1, (NN + 63) / 64);
    gemm_f32s<64, 64, 8, 4, 4><<<gsmall, 256, 0, stream>>>(nump, 5, w_num, 64, b_num, x, HD, 128, NN, 64, 5);
    gemm_f32s<64, 64, 8, 4, 4><<<gsmall, 256, 0, stream>>>(catp, 3, w_cat, 64, b_cat, x, HD, 192, NN, 64, 3);

    // ---- y = lrelu(x @ w_in + b_in) ----
    dim3 gbig(HD / 128, (NN + 127) / 128);
    gemm_mfma<128, 128, 1><<<gbig, 256, 0, stream>>>(x, HD, win_h, win_l, b_in, y, HD, 0, NN, HD);

    // ---- RGCN layer 1 ----
    gemm_mfma<128, 128, 2><<<gbig, 256, 0, stream>>>(y, HD, w1ah, w1al, bias1, hrel,                   HD, 0, NN, HD);
    gemm_mfma<128, 128, 2><<<gbig, 256, 0, stream>>>(y, HD, w1bh, w1bl, bias1, hrel + (size_t)NN * HD, HD, 0, NN, HD);
    gemm_mfma<128, 128, 2><<<gbig, 256, 0, stream>>>(y, HD, r1h,  r1l,  bias1, x,                      HD, 0, NN, HD);
    gather_mean<<<(NN + 3) / 4, 256, 0, stream>>>(hrel, offs, srcl, x);

    // ---- RGCN layer 2 ----
    gemm_mfma<128, 128, 2><<<gbig, 256, 0, stream>>>(x, HD, w2ah, w2al, bias2, hrel,                   HD, 0, NN, HD);
    gemm_mfma<128, 128, 2><<<gbig, 256, 0, stream>>>(x, HD, w2bh, w2bl, bias2, hrel + (size_t)NN * HD, HD, 0, NN, HD);
    gemm_mfma<128, 128, 2><<<gbig, 256, 0, stream>>>(x, HD, r2h,  r2l,  bias2, y,                      HD, 0, NN, HD);
    gather_mean<<<(NN + 3) / 4, 256, 0, stream>>>(hrel, offs, srcl, y);

    // ---- logits ----
    out_proj<<<(NN + 3) / 4, 256, 0, stream>>>(y, w_out, b_out, outp);
}

// Round 5
// 828.217 us; speedup vs baseline: 3.7153x; 1.2188x over previous
//
#include <hip/hip_runtime.h>

#define NN 50000
#define EE 800000
#define HD 256
#define NSEG (2 * NN)
#define CHUNK 2048
#define NB ((NSEG + CHUNK - 1) / CHUNK)

typedef unsigned short u16;
typedef short bf16x8 __attribute__((ext_vector_type(8)));
typedef float f32x4 __attribute__((ext_vector_type(4)));

__device__ __forceinline__ u16 f2bf_rne(float f) {
    unsigned u = __float_as_uint(f);
    return (u16)((u + 0x7FFF + ((u >> 16) & 1)) >> 16);
}
// trunc hi + RNE residual: (h,l) represents v to ~2^-17 relative
__device__ __forceinline__ void split_tr(float v, u16& h, u16& l) {
    unsigned u = __float_as_uint(v);
    h = (u16)(u >> 16);
    l = f2bf_rne(v - __uint_as_float(u & 0xFFFF0000u));
}

// ============ proj GEMM: A f32 (split per-tile), B bf16 hi/lo, out bf16 pair ============
// lrelu activation. LDS fragment-major: tile[(g*DIM + rc)*8 + j] = elem k0+g*8+j, g=lane>>4.
template<int BM, int BN>
__global__ __launch_bounds__(256) void gemm_f32a(
    const float* __restrict__ A, int lda,
    const u16* __restrict__ Bh, const u16* __restrict__ Bl,
    const float* __restrict__ bias,
    u16* __restrict__ Ch, u16* __restrict__ Cl, int coff,
    int M, int K)
{
    constexpr int WM = BM / 2, WN = BN / 2;
    constexpr int MI = WM / 16, NI = WN / 16;
    constexpr int APT = (BM * 8) / 256;
    constexpr int BPT = (BN * 4) / 256;

    __shared__ __align__(16) u16 Ash[4 * BM * 8];
    __shared__ __align__(16) u16 Asl[4 * BM * 8];
    __shared__ __align__(16) u16 Bsh[4 * BN * 8];
    __shared__ __align__(16) u16 Bsl[4 * BN * 8];

    const int tid = threadIdx.x;
    const int lane = tid & 63;
    const int w = tid >> 6;
    const int wr = w >> 1, wc = w & 1;
    const int brow = blockIdx.y * BM, bcol = blockIdx.x * BN;
    const int r15 = lane & 15, g = lane >> 4;

    f32x4 acc[MI][NI];
#pragma unroll
    for (int mi = 0; mi < MI; mi++)
#pragma unroll
        for (int ni = 0; ni < NI; ni++) acc[mi][ni] = (f32x4){0.f, 0.f, 0.f, 0.f};

    for (int k0 = 0; k0 < K; k0 += 32) {
#pragma unroll
        for (int s = 0; s < APT; s++) {
            int slot = tid + s * 256;
            int row = slot >> 3, k4 = (slot & 7) * 4;
            float4 v = {0.f, 0.f, 0.f, 0.f};
            int gr = brow + row;
            if (gr < M) v = *(const float4*)&A[(size_t)gr * lda + k0 + k4];
            float vf[4] = {v.x, v.y, v.z, v.w};
            unsigned long long ph = 0, pl = 0;
#pragma unroll
            for (int j = 0; j < 4; j++) {
                u16 h, l; split_tr(vf[j], h, l);
                ph |= ((unsigned long long)h) << (16 * j);
                pl |= ((unsigned long long)l) << (16 * j);
            }
            int base = ((k4 >> 3) * BM + row) * 8 + (k4 & 7);
            *(unsigned long long*)&Ash[base] = ph;
            *(unsigned long long*)&Asl[base] = pl;
        }
#pragma unroll
        for (int s = 0; s < BPT; s++) {
            int c = tid + s * 256;
            int col = c & (BN - 1), gg = c / BN;
            size_t off = (size_t)(bcol + col) * K + k0 + gg * 8;
            *(uint4*)&Bsh[(gg * BN + col) * 8] = *(const uint4*)&Bh[off];
            *(uint4*)&Bsl[(gg * BN + col) * 8] = *(const uint4*)&Bl[off];
        }
        __syncthreads();

        bf16x8 afh[MI], afl[MI], bfh[NI], bfl[NI];
#pragma unroll
        for (int mi = 0; mi < MI; mi++) {
            int idx = (g * BM + wr * WM + mi * 16 + r15) * 8;
            afh[mi] = *(const bf16x8*)&Ash[idx];
            afl[mi] = *(const bf16x8*)&Asl[idx];
        }
#pragma unroll
        for (int ni = 0; ni < NI; ni++) {
            int idx = (g * BN + wc * WN + ni * 16 + r15) * 8;
            bfh[ni] = *(const bf16x8*)&Bsh[idx];
            bfl[ni] = *(const bf16x8*)&Bsl[idx];
        }
#pragma unroll
        for (int mi = 0; mi < MI; mi++)
#pragma unroll
            for (int ni = 0; ni < NI; ni++)
                acc[mi][ni] = __builtin_amdgcn_mfma_f32_16x16x32_bf16(afh[mi], bfh[ni], acc[mi][ni], 0, 0, 0);
#pragma unroll
        for (int mi = 0; mi < MI; mi++)
#pragma unroll
            for (int ni = 0; ni < NI; ni++)
                acc[mi][ni] = __builtin_amdgcn_mfma_f32_16x16x32_bf16(afl[mi], bfh[ni], acc[mi][ni], 0, 0, 0);
#pragma unroll
        for (int mi = 0; mi < MI; mi++)
#pragma unroll
            for (int ni = 0; ni < NI; ni++)
                acc[mi][ni] = __builtin_amdgcn_mfma_f32_16x16x32_bf16(afh[mi], bfl[ni], acc[mi][ni], 0, 0, 0);
        __syncthreads();
    }

#pragma unroll
    for (int mi = 0; mi < MI; mi++) {
#pragma unroll
        for (int ni = 0; ni < NI; ni++) {
            int col = bcol + wc * WN + ni * 16 + r15;
            float bsv = bias[col];
            int rbase = brow + wr * WM + mi * 16 + g * 4;
#pragma unroll
            for (int r = 0; r < 4; r++) {
                int grow = rbase + r;
                if (grow >= M) continue;
                float v = acc[mi][ni][r] + bsv;
                v = v > 0.f ? v : 0.01f * v;   // lrelu
                u16 h, l; split_tr(v, h, l);
                Ch[(size_t)grow * HD + coff + col] = h;
                Cl[(size_t)grow * HD + coff + col] = l;
            }
        }
    }
}

// ============ bf16-A GEMM (A pre-split hi/lo, lda=K=256) ============
// MODE 1: out = bf16 pair (O1h/O1l), lrelu, bias[col]          (w_in)
// MODE 2: cols<512 -> relu -> RNE bf16 into hrel=O1h; cols>=512 -> relu -> f32 O2
//         bias[col&255]                                         (fused layer)
template<int BM, int BN, int MODE>
__global__ __launch_bounds__(256) void gemm_bf16a(
    const u16* __restrict__ Ahg, const u16* __restrict__ Alg,
    const u16* __restrict__ Bh, const u16* __restrict__ Bl,
    const float* __restrict__ bias,
    u16* __restrict__ O1h, u16* __restrict__ O1l,
    float* __restrict__ O2,
    int M, int K)
{
    constexpr int WM = BM / 2, WN = BN / 2;
    constexpr int MI = WM / 16, NI = WN / 16;
    constexpr int ACH = (BM * 4) / 256;   // 16B chunks per thread (A)
    constexpr int BCH = (BN * 4) / 256;

    __shared__ __align__(16) u16 Ash[4 * BM * 8];
    __shared__ __align__(16) u16 Asl[4 * BM * 8];
    __shared__ __align__(16) u16 Bsh[4 * BN * 8];
    __shared__ __align__(16) u16 Bsl[4 * BN * 8];

    const int tid = threadIdx.x;
    const int lane = tid & 63;
    const int w = tid >> 6;
    const int wr = w >> 1, wc = w & 1;
    const int brow = blockIdx.y * BM, bcol = blockIdx.x * BN;
    const int r15 = lane & 15, g = lane >> 4;

    f32x4 acc[MI][NI];
#pragma unroll
    for (int mi = 0; mi < MI; mi++)
#pragma unroll
        for (int ni = 0; ni < NI; ni++) acc[mi][ni] = (f32x4){0.f, 0.f, 0.f, 0.f};

    for (int k0 = 0; k0 < K; k0 += 32) {
#pragma unroll
        for (int s = 0; s < ACH; s++) {
            int c = tid + s * 256;
            int row = c >> 2, gg = c & 3;
            int gr = brow + row;
            uint4 vh = {0, 0, 0, 0}, vl = {0, 0, 0, 0};
            if (gr < M) {
                size_t off = (size_t)gr * HD + k0 + gg * 8;
                vh = *(const uint4*)&Ahg[off];
                vl = *(const uint4*)&Alg[off];
            }
            *(uint4*)&Ash[(gg * BM + row) * 8] = vh;
            *(uint4*)&Asl[(gg * BM + row) * 8] = vl;
        }
#pragma unroll
        for (int s = 0; s < BCH; s++) {
            int c = tid + s * 256;
            int col = c & (BN - 1), gg = c / BN;
            size_t off = (size_t)(bcol + col) * K + k0 + gg * 8;
            *(uint4*)&Bsh[(gg * BN + col) * 8] = *(const uint4*)&Bh[off];
            *(uint4*)&Bsl[(gg * BN + col) * 8] = *(const uint4*)&Bl[off];
        }
        __syncthreads();

        bf16x8 afh[MI], afl[MI], bfh[NI], bfl[NI];
#pragma unroll
        for (int mi = 0; mi < MI; mi++) {
            int idx = (g * BM + wr * WM + mi * 16 + r15) * 8;
            afh[mi] = *(const bf16x8*)&Ash[idx];
            afl[mi] = *(const bf16x8*)&Asl[idx];
        }
#pragma unroll
        for (int ni = 0; ni < NI; ni++) {
            int idx = (g * BN + wc * WN + ni * 16 + r15) * 8;
            bfh[ni] = *(const bf16x8*)&Bsh[idx];
            bfl[ni] = *(const bf16x8*)&Bsl[idx];
        }
#pragma unroll
        for (int mi = 0; mi < MI; mi++)
#pragma unroll
            for (int ni = 0; ni < NI; ni++)
                acc[mi][ni] = __builtin_amdgcn_mfma_f32_16x16x32_bf16(afh[mi], bfh[ni], acc[mi][ni], 0, 0, 0);
#pragma unroll
        for (int mi = 0; mi < MI; mi++)
#pragma unroll
            for (int ni = 0; ni < NI; ni++)
                acc[mi][ni] = __builtin_amdgcn_mfma_f32_16x16x32_bf16(afl[mi], bfh[ni], acc[mi][ni], 0, 0, 0);
#pragma unroll
        for (int mi = 0; mi < MI; mi++)
#pragma unroll
            for (int ni = 0; ni < NI; ni++)
                acc[mi][ni] = __builtin_amdgcn_mfma_f32_16x16x32_bf16(afh[mi], bfl[ni], acc[mi][ni], 0, 0, 0);
        __syncthreads();
    }

#pragma unroll
    for (int mi = 0; mi < MI; mi++) {
#pragma unroll
        for (int ni = 0; ni < NI; ni++) {
            int col = bcol + wc * WN + ni * 16 + r15;
            float bsv = bias[col & (HD - 1)];
            int rbase = brow + wr * WM + mi * 16 + g * 4;
#pragma unroll
            for (int r = 0; r < 4; r++) {
                int grow = rbase + r;
                if (grow >= M) continue;
                float v = acc[mi][ni][r] + bsv;
                if (MODE == 1) {
                    v = v > 0.f ? v : 0.01f * v;   // lrelu
                    u16 h, l; split_tr(v, h, l);
                    O1h[(size_t)grow * HD + col] = h;
                    O1l[(size_t)grow * HD + col] = l;
                } else {
                    v = fmaxf(v, 0.f);             // relu
                    if (col < 2 * HD) {
                        O1h[((size_t)(col >> 8) * NN + grow) * HD + (col & (HD - 1))] = f2bf_rne(v);
                    } else {
                        O2[(size_t)grow * HD + (col & (HD - 1))] = v;
                    }
                }
            }
        }
    }
}

// ---- weight split+transpose: W f32 [K][Ncol] -> T bf16 [colOff+n][K] hi/lo ----
__global__ void conv_w(const float* __restrict__ W, int K, int Ncol,
                       u16* __restrict__ Th, u16* __restrict__ Tl, int colOff)
{
    int i = blockIdx.x * 256 + threadIdx.x;
    if (i >= K * Ncol) return;
    int k = i / Ncol, n = i % Ncol;
    u16 h, l; split_tr(W[i], h, l);
    Th[(size_t)(colOff + n) * K + k] = h;
    Tl[(size_t)(colOff + n) * K + k] = l;
}

// ---------------- small f32 GEMM (K=5/3), bf16-pair out ----------------
template<int BM, int BN, int BK, int TM, int TN>
__global__ __launch_bounds__(256) void gemm_f32s(
    const float* __restrict__ A, int lda,
    const float* __restrict__ B, int ldb,
    const float* __restrict__ bias,
    u16* __restrict__ Ch, u16* __restrict__ Cl, int coff,
    int M, int Ncol, int K)
{
    constexpr int TX = BN / TN;
    __shared__ float As[BK][BM + 4];
    __shared__ float Bs[BK][BN + 4];
    const int tid = threadIdx.x;
    const int tx = tid % TX, ty = tid / TX;
    const int brow = blockIdx.y * BM;
    const int bcol = blockIdx.x * BN;
    float acc[TM][TN];
#pragma unroll
    for (int i = 0; i < TM; i++)
#pragma unroll
        for (int j = 0; j < TN; j++) acc[i][j] = 0.f;
    for (int k0 = 0; k0 < K; k0 += BK) {
#pragma unroll
        for (int idx = tid; idx < BM * BK; idx += 256) {
            int m = idx / BK, k = idx % BK;
            int gr = brow + m, gk = k0 + k;
            As[k][m] = (gr < M && gk < K) ? A[(size_t)gr * lda + gk] : 0.f;
        }
#pragma unroll
        for (int idx = tid; idx < BK * BN; idx += 256) {
            int k = idx / BN, n = idx % BN;
            int gk = k0 + k, gc = bcol + n;
            Bs[k][n] = (gk < K && gc < Ncol) ? B[(size_t)gk * ldb + gc] : 0.f;
        }
        __syncthreads();
#pragma unroll
        for (int k = 0; k < BK; k++) {
            float a[TM], b[TN];
#pragma unroll
            for (int i = 0; i < TM; i++) a[i] = As[k][ty * TM + i];
#pragma unroll
            for (int j = 0; j < TN; j++) b[j] = Bs[k][tx * TN + j];
#pragma unroll
            for (int i = 0; i < TM; i++)
#pragma unroll
                for (int j = 0; j < TN; j++) acc[i][j] = fmaf(a[i], b[j], acc[i][j]);
        }
        __syncthreads();
    }
#pragma unroll
    for (int i = 0; i < TM; i++) {
        int gr = brow + ty * TM + i;
        if (gr >= M) continue;
#pragma unroll
        for (int j = 0; j < TN; j++) {
            int gc = bcol + tx * TN + j;
            if (gc >= Ncol) continue;
            float v = acc[i][j] + bias[gc];
            v = v > 0.f ? v : 0.01f * v;
            u16 h, l; split_tr(v, h, l);
            Ch[(size_t)gr * HD + coff + gc] = h;
            Cl[(size_t)gr * HD + coff + gc] = l;
        }
    }
}

// ---------------- CSR build ----------------
__global__ void count_seg(const int* __restrict__ ei, const int* __restrict__ et,
                          int* __restrict__ segc)
{
    int e = blockIdx.x * blockDim.x + threadIdx.x;
    if (e < EE) {
        int dst = ei[EE + e];
        int r = et[e];
        atomicAdd(&segc[r * NN + dst], 1);
    }
}

__global__ __launch_bounds__(256) void scan_local(const int* __restrict__ segc,
                                                  int* __restrict__ offs,
                                                  int* __restrict__ bsum)
{
    int b = blockIdx.x;
    int base = b * CHUNK;
    int tid = threadIdx.x;
    int lane = tid & 63, wave = tid >> 6;
    __shared__ int wsum[4];
    int vals[8];
    int i0 = base + tid * 8;
    int s = 0;
    if (i0 + 7 < NSEG) {
        int4 v0 = *(const int4*)&segc[i0];
        int4 v1 = *(const int4*)&segc[i0 + 4];
        vals[0] = v0.x; vals[1] = v0.y; vals[2] = v0.z; vals[3] = v0.w;
        vals[4] = v1.x; vals[5] = v1.y; vals[6] = v1.z; vals[7] = v1.w;
    } else {
#pragma unroll
        for (int j = 0; j < 8; j++) vals[j] = (i0 + j < NSEG) ? segc[i0 + j] : 0;
    }
#pragma unroll
    for (int j = 0; j < 8; j++) s += vals[j];
    int v = s;
#pragma unroll
    for (int off = 1; off < 64; off <<= 1) {
        int u = __shfl_up(v, off);
        if (lane >= off) v += u;
    }
    if (lane == 63) wsum[wave] = v;
    __syncthreads();
    int wbase = 0;
#pragma unroll
    for (int ww = 0; ww < 4; ww++) if (ww < wave) wbase += wsum[ww];
    int run = wbase + v - s;
#pragma unroll
    for (int j = 0; j < 8; j++) {
        run += vals[j];
        int i = i0 + j;
        if (i < NSEG) offs[i + 1] = run;
    }
    if (tid == 0) {
        int t = 0;
#pragma unroll
        for (int ww = 0; ww < 4; ww++) t += wsum[ww];
        bsum[b] = t;
    }
}

__global__ void scan_bsum(const int* __restrict__ bsum, int* __restrict__ bbase)
{
    int lane = threadIdx.x;
    int c = (lane < NB) ? bsum[lane] : 0;
    int v = c;
#pragma unroll
    for (int off = 1; off < 64; off <<= 1) {
        int u = __shfl_up(v, off);
        if (lane >= off) v += u;
    }
    if (lane < NB) bbase[lane] = v - c;
}

__global__ void add_base(int* __restrict__ offs, const int* __restrict__ bbase)
{
    int i = blockIdx.x * blockDim.x + threadIdx.x;
    if (i < NSEG) offs[i + 1] += bbase[i / CHUNK];
    if (i == 0) offs[0] = 0;
}

__global__ void fill_src(const int* __restrict__ ei, const int* __restrict__ et,
                         const int* __restrict__ offs, int* __restrict__ cursor,
                         int* __restrict__ src_list)
{
    int e = blockIdx.x * blockDim.x + threadIdx.x;
    if (e < EE) {
        int src = ei[e];
        int dst = ei[EE + e];
        int s = et[e] * NN + dst;
        int pos = offs[s] + atomicAdd(&cursor[s], 1);
        src_list[pos] = src;
    }
}

// ---------------- gather: v = base + sum_r mean(hrel_bf16) ----------------
// OUTM 0: write bf16 hi/lo pair (Oh/Ol).  OUTM 1: write f32 Of (may alias base).
template<int OUTM>
__global__ __launch_bounds__(256) void gather_mean_b(
    const u16* __restrict__ hrelb,
    const int* __restrict__ offs,
    const int* __restrict__ src_list,
    const float* __restrict__ basein,
    u16* __restrict__ Oh, u16* __restrict__ Ol,
    float* __restrict__ Of)
{
    int d = blockIdx.x * 4 + (threadIdx.x >> 6);
    if (d >= NN) return;
    int lane = threadIdx.x & 63;
    f32x4 acc = {0.f, 0.f, 0.f, 0.f};
#pragma unroll
    for (int r = 0; r < 2; r++) {
        int s = r * NN + d;
        int start = offs[s], end = offs[s + 1];
        if (start == end) continue;
        f32x4 a = {0.f, 0.f, 0.f, 0.f};
        const u16* hb = hrelb + (size_t)r * NN * HD;
        for (int i = start; i < end; i++) {
            int src = src_list[i];
            uint2 wv = *(const uint2*)(hb + (size_t)src * HD + lane * 4);
            a.x += __uint_as_float(wv.x << 16);
            a.y += __uint_as_float(wv.x & 0xFFFF0000u);
            a.z += __uint_as_float(wv.y << 16);
            a.w += __uint_as_float(wv.y & 0xFFFF0000u);
        }
        float inv = 1.0f / (float)(end - start);
        acc.x += a.x * inv; acc.y += a.y * inv;
        acc.z += a.z * inv; acc.w += a.w * inv;
    }
    float4 b = ((const float4*)(basein + (size_t)d * HD))[lane];
    float v0 = b.x + acc.x, v1 = b.y + acc.y, v2 = b.z + acc.z, v3 = b.w + acc.w;
    if (OUTM == 0) {
        u16 h0, l0, h1, l1, h2, l2, h3, l3;
        split_tr(v0, h0, l0); split_tr(v1, h1, l1);
        split_tr(v2, h2, l2); split_tr(v3, h3, l3);
        uint2 uh, ul;
        uh.x = (unsigned)h0 | ((unsigned)h1 << 16);
        uh.y = (unsigned)h2 | ((unsigned)h3 << 16);
        ul.x = (unsigned)l0 | ((unsigned)l1 << 16);
        ul.y = (unsigned)l2 | ((unsigned)l3 << 16);
        *(uint2*)(Oh + (size_t)d * HD + lane * 4) = uh;
        *(uint2*)(Ol + (size_t)d * HD + lane * 4) = ul;
    } else {
        float4 o = {v0, v1, v2, v3};
        ((float4*)(Of + (size_t)d * HD))[lane] = o;
    }
}

// ---------------- output head ----------------
__global__ __launch_bounds__(256) void out_proj(
    const float* __restrict__ x, const float* __restrict__ w,
    const float* __restrict__ b, float* __restrict__ out)
{
    int n = blockIdx.x * 4 + (threadIdx.x >> 6);
    if (n >= NN) return;
    int lane = threadIdx.x & 63;
    const float4* xr4 = (const float4*)(x + (size_t)n * HD);
    float4 v = xr4[lane];
    int k = lane * 4;
    float a0 = v.x * w[(k + 0) * 2 + 0] + v.y * w[(k + 1) * 2 + 0]
             + v.z * w[(k + 2) * 2 + 0] + v.w * w[(k + 3) * 2 + 0];
    float a1 = v.x * w[(k + 0) * 2 + 1] + v.y * w[(k + 1) * 2 + 1]
             + v.z * w[(k + 2) * 2 + 1] + v.w * w[(k + 3) * 2 + 1];
#pragma unroll
    for (int off = 32; off > 0; off >>= 1) {
        a0 += __shfl_down(a0, off);
        a1 += __shfl_down(a1, off);
    }
    if (lane == 0) {
        out[(size_t)n * 2 + 0] = a0 + b[0];
        out[(size_t)n * 2 + 1] = a1 + b[1];
    }
}

extern "C" void kernel_launch(void* const* d_in, const int* in_sizes, int n_in,
                              void* d_out, int out_size, void* d_ws, size_t ws_size,
                              hipStream_t stream)
{
    const float* des   = (const float*)d_in[0];
    const float* tweet = (const float*)d_in[1];
    const float* nump  = (const float*)d_in[2];
    const float* catp  = (const float*)d_in[3];
    const int*   ei    = (const int*)d_in[4];
    const int*   et    = (const int*)d_in[5];
    const float* w_des = (const float*)d_in[6],  *b_des = (const float*)d_in[7];
    const float* w_tw  = (const float*)d_in[8],  *b_tw  = (const float*)d_in[9];
    const float* w_num = (const float*)d_in[10], *b_num = (const float*)d_in[11];
    const float* w_cat = (const float*)d_in[12], *b_cat = (const float*)d_in[13];
    const float* w_in  = (const float*)d_in[14], *b_in  = (const float*)d_in[15];
    const float* weight1 = (const float*)d_in[16], *root1 = (const float*)d_in[17], *bias1 = (const float*)d_in[18];
    const float* weight2 = (const float*)d_in[19], *root2 = (const float*)d_in[20], *bias2 = (const float*)d_in[21];
    const float* w_out = (const float*)d_in[22], *b_out = (const float*)d_in[23];
    float* outp = (float*)d_out;

    const int HSZ = HD * HD, PSZ = 768 * 64;

    // ---- workspace carve-up ----
    float* base  = (float*)d_ws;                       // [N,HD] f32 (root out / final)
    u16*   hrelb = (u16*)(base + (size_t)NN * HD);     // [2,N,HD] bf16
    u16*   xh    = hrelb + (size_t)2 * NN * HD;
    u16*   xl    = xh + (size_t)NN * HD;
    u16*   yh    = xl + (size_t)NN * HD;
    u16*   yl    = yh + (size_t)NN * HD;
    int*   offs  = (int*)(yl + (size_t)NN * HD);
    int*   segc  = offs + (NSEG + 1);
    int*   srcl  = segc + NSEG;
    int*   bsum  = srcl + EE;
    int*   bbase = bsum + NB;
    uintptr_t wp = ((uintptr_t)(bbase + NB) + 15) & ~(uintptr_t)15;
    u16* desBh = (u16*)wp;          u16* desBl = desBh + PSZ;
    u16* twBh  = desBl + PSZ;       u16* twBl  = twBh + PSZ;
    u16* winBh = twBl + PSZ;        u16* winBl = winBh + HSZ;
    u16* cat1h = winBl + HSZ;       u16* cat1l = cat1h + 3 * HSZ;
    u16* cat2h = cat1l + 3 * HSZ;   u16* cat2l = cat2h + 3 * HSZ;

    // ---- CSR build ----
    hipMemsetAsync(segc, 0, NSEG * sizeof(int), stream);
    count_seg<<<(EE + 255) / 256, 256, 0, stream>>>(ei, et, segc);
    scan_local<<<NB, 256, 0, stream>>>(segc, offs, bsum);
    scan_bsum<<<1, 64, 0, stream>>>(bsum, bbase);
    add_base<<<(NSEG + 255) / 256, 256, 0, stream>>>(offs, bbase);
    hipMemsetAsync(segc, 0, NSEG * sizeof(int), stream);
    fill_src<<<(EE + 255) / 256, 256, 0, stream>>>(ei, et, offs, segc, srcl);

    // ---- weight split+transpose ----
    conv_w<<<(PSZ + 255) / 256, 256, 0, stream>>>(w_des, 768, 64, desBh, desBl, 0);
    conv_w<<<(PSZ + 255) / 256, 256, 0, stream>>>(w_tw,  768, 64, twBh,  twBl,  0);
    conv_w<<<(HSZ + 255) / 256, 256, 0, stream>>>(w_in, HD, HD, winBh, winBl, 0);
    conv_w<<<(HSZ + 255) / 256, 256, 0, stream>>>(weight1,       HD, HD, cat1h, cat1l, 0);
    conv_w<<<(HSZ + 255) / 256, 256, 0, stream>>>(weight1 + HSZ, HD, HD, cat1h, cat1l, 256);
    conv_w<<<(HSZ + 255) / 256, 256, 0, stream>>>(root1,         HD, HD, cat1h, cat1l, 512);
    conv_w<<<(HSZ + 255) / 256, 256, 0, stream>>>(weight2,       HD, HD, cat2h, cat2l, 0);
    conv_w<<<(HSZ + 255) / 256, 256, 0, stream>>>(weight2 + HSZ, HD, HD, cat2h, cat2l, 256);
    conv_w<<<(HSZ + 255) / 256, 256, 0, stream>>>(root2,         HD, HD, cat2h, cat2l, 512);

    // ---- feature projections -> xh/xl ----
    dim3 gproj(1, (NN + 127) / 128);
    gemm_f32a<128, 64><<<gproj, 256, 0, stream>>>(des,   768, desBh, desBl, b_des, xh, xl, 0,  NN, 768);
    gemm_f32a<128, 64><<<gproj, 256, 0, stream>>>(tweet, 768, twBh,  twBl,  b_tw,  xh, xl, 64, NN, 768);
    dim3 gsmall(1, (NN + 63) / 64);
    gemm_f32s<64, 64, 8, 4, 4><<<gsmall, 256, 0, stream>>>(nump, 5, w_num, 64, b_num, xh, xl, 128, NN, 64, 5);
    gemm_f32s<64, 64, 8, 4, 4><<<gsmall, 256, 0, stream>>>(catp, 3, w_cat, 64, b_cat, xh, xl, 192, NN, 64, 3);

    // ---- y = lrelu(x @ w_in + b_in) -> yh/yl ----
    dim3 gwin(HD / 128, (NN + 127) / 128);
    gemm_bf16a<128, 128, 1><<<gwin, 256, 0, stream>>>(xh, xl, winBh, winBl, b_in, yh, yl, nullptr, NN, HD);

    // ---- layer 1: fused [W_r0|W_r1|root1] -> hrelb (bf16) + base (f32) ----
    dim3 glay(768 / 128, (NN + 127) / 128);
    gemm_bf16a<128, 128, 2><<<glay, 256, 0, stream>>>(yh, yl, cat1h, cat1l, bias1, hrelb, nullptr, base, NN, HD);
    gather_mean_b<0><<<(NN + 3) / 4, 256, 0, stream>>>(hrelb, offs, srcl, base, xh, xl, nullptr);

    // ---- layer 2 ----
    gemm_bf16a<128, 128, 2><<<glay, 256, 0, stream>>>(xh, xl, cat2h, cat2l, bias2, hrelb, nullptr, base, NN, HD);
    gather_mean_b<1><<<(NN + 3) / 4, 256, 0, stream>>>(hrelb, offs, srcl, base, nullptr, nullptr, base);

    // ---- logits ----
    out_proj<<<(NN + 3) / 4, 256, 0, stream>>>(base, w_out, b_out, outp);
}